// Round 14
// baseline (621.422 us; speedup 1.0000x reference)
//
#include <hip/hip_runtime.h>

typedef float f32x2 __attribute__((ext_vector_type(2)));
typedef float f32x4 __attribute__((ext_vector_type(4)));

#define NN 16384
#define NCB 8
#define DIM 32
#define CB 1024

// packed 2xFP32 FMA; each half bit-identical to scalar fmaf (frozen chain).
__device__ __forceinline__ f32x2 pkfma(f32x2 a, f32x2 b, f32x2 c) {
    f32x2 d = c;
    asm("v_pk_fma_f32 %0, %1, %2, %0" : "+v"(d) : "v"(a), "v"(b));
    return d;
}

// Precompute: csqb[k*CB+c] = ||c||^2 + bias; xsqb[p] = ||x_p||^2 (frozen
// chains, identical to R12 which passed absmax 0).
__global__ __launch_bounds__(256) void vq_pre(const float* __restrict__ cb,
                                              const float* __restrict__ rb,
                                              const float* __restrict__ x,
                                              float* __restrict__ csqb,
                                              float* __restrict__ xsqb) {
    const int gid = blockIdx.x * 256 + threadIdx.x;
    if (gid < NCB * CB) {
        const f32x4* c4 = (const f32x4*)(cb + (size_t)gid * DIM);
        float s0 = 0.f, s1 = 0.f, s2 = 0.f, s3 = 0.f;
#pragma unroll
        for (int j = 0; j < 8; ++j) {
            f32x4 v = c4[j];
            s0 = fmaf(v.x, v.x, s0);
            s1 = fmaf(v.y, v.y, s1);
            s2 = fmaf(v.z, v.z, s2);
            s3 = fmaf(v.w, v.w, s3);
        }
        csqb[gid] = ((s0 + s1) + (s2 + s3)) + rb[gid];
    }
    const int p = gid - NCB * CB;
    if (p >= 0 && p < NN * NCB) {
        const f32x4* x4 = (const f32x4*)(x + (size_t)p * DIM);
        float q0 = 0.f, q1 = 0.f, q2 = 0.f, q3 = 0.f;
#pragma unroll
        for (int j = 0; j < 8; ++j) {
            f32x4 v = x4[j];
            q0 = fmaf(v.x, v.x, q0);
            q1 = fmaf(v.y, v.y, q1);
            q2 = fmaf(v.z, v.z, q2);
            q3 = fmaf(v.w, v.w, q3);
        }
        xsqb[p] = (q0 + q1) + (q2 + q3);
    }
}

// Fused kernel: 256 blocks (1/CU, 128 KB LDS) x 512 threads (8 waves).
// GEMM-style register tiling: wave w owns row band [w*64,+64); lane (ri,ci)
// computes an 8-row x 4-entry tile. cb k-slice staged ONCE into XOR-swizzled
// LDS [chunk][entry] (swz: byte ^= (e-bits3-4)<<4). Swizzle audit:
//   write(e,c):  addr = (c<<14)|(e<<4),  addr ^= ((addr>>7)&3)<<4
//   read(ee):    addr = (c<<14)|((e0+ee)<<4), SAME xor (e0+ee never carries
//                into bit 3+ since e0%4==0, ee<4)  -> mapping matches.
//   banks: per instr the 8 ci lanes land on {bit6=ci0, bits4-5=ee^ci12} ->
//   8 disjoint 4-bank groups = all 32 banks; ri lanes broadcast.
// Staging: wave w stages chunk-plane c=w, lane->entry: LDS writes are
// consecutive 16B (2 lanes/bank = free); global reads stride-128 (L2-hot).
// x fragments stream from global/L1 (separate pipe from LDS). Per K-chunk:
// 4 ds_read_b128 + 8 global b128 + 64 pkfma (frozen 4-acc chain). one_hot
// zero-fill: 1 store/chunk-iter on the wave's own 64 rows; per-wave
// vmcnt(0) orders them before the 1.0 scatter -> no barriers after staging.
__global__ __launch_bounds__(512, 2) void vq_fused(
    const float* __restrict__ x, const float* __restrict__ cb,
    const float* __restrict__ csqb, const float* __restrict__ xsqb,
    float* __restrict__ xhat, float* __restrict__ onehot,
    float* __restrict__ idxf) {
    __shared__ char cbP[131072];  // 128 KB swizzled [chunk][entry] f32x4

    const int tid = threadIdx.x;
    const int w = tid >> 6;
    const int lane = tid & 63;
    const int ri = lane >> 3;  // row group within wave tile
    const int ci = lane & 7;   // entry group within wave tile
    const int k = blockIdx.x & (NCB - 1);
    const int n0 = (blockIdx.x >> 3) * 512;

    const f32x4* cbk4 = (const f32x4*)(cb + (size_t)k * CB * DIM);

    // ---- stage cb slice: wave w = chunk-plane w, lane -> entry ----
#pragma unroll
    for (int it = 0; it < 16; ++it) {
        const int e = it * 64 + lane;
        const f32x4 v = cbk4[(size_t)e * 8 + w];
        unsigned addr = ((unsigned)w << 14) | ((unsigned)e << 4);
        addr ^= ((addr >> 7) & 3) << 4;
        *(f32x4*)(cbP + addr) = v;
    }
    __syncthreads();  // staging visible; no stores outstanding yet

    // ---- this lane's 8 rows ----
    const int row0 = n0 + w * 64 + ri * 8;
    float xs[8];
#pragma unroll
    for (int rr = 0; rr < 8; ++rr)
        xs[rr] = xsqb[(size_t)(row0 + rr) * NCB + k];
    const float* xbase = x + ((size_t)row0 * NCB + k) * DIM;  // rr stride 256

    float bestd[8];
    int bib[8];
#pragma unroll
    for (int rr = 0; rr < 8; ++rr) {
        bestd[rr] = 3.4028235e38f;
        bib[rr] = 0;
    }

    float4* oh4 = (float4*)onehot;
    const float4 z4 = {0.f, 0.f, 0.f, 0.f};

    for (int ct = 0; ct < 32; ++ct) {  // 32 col-tiles of 32 entries
        const int e0 = ct * 32 + ci * 4;
        const f32x4 cq4 = *(const f32x4*)(csqb + (size_t)k * CB + e0);
        f32x2 A01[8][4], A23[8][4];
#pragma unroll
        for (int rr = 0; rr < 8; ++rr)
#pragma unroll
            for (int ee = 0; ee < 4; ++ee) {
                A01[rr][ee] = (f32x2){0.f, 0.f};
                A23[rr][ee] = (f32x2){0.f, 0.f};
            }

#pragma unroll
        for (int c = 0; c < 8; ++c) {  // K chunks of 4 dims
            // interleaved zero-fill: this wave's own 64 rows, 1 KB/store
            {
                const int s = ct * 8 + c;
                oh4[((size_t)(n0 + w * 64 + (s >> 2)) * NCB + k) * 256 +
                    (s & 3) * 64 + lane] = z4;
            }
            // cb fragments from swizzled LDS (full addr incl. ee, THEN xor)
            f32x4 cbf[4];
#pragma unroll
            for (int ee = 0; ee < 4; ++ee) {
                unsigned addr =
                    ((unsigned)c << 14) | ((unsigned)(e0 + ee) << 4);
                addr ^= ((addr >> 7) & 3) << 4;
                cbf[ee] = *(const f32x4*)(cbP + addr);
            }
            // x fragments (global, L1/L2-hot)
            f32x4 xf[8];
#pragma unroll
            for (int rr = 0; rr < 8; ++rr)
                xf[rr] = *(const f32x4*)(xbase + rr * 256 + c * 4);
            // frozen chain: A01=(d0,d1), A23=(d2,d3), chunks ascending
#pragma unroll
            for (int rr = 0; rr < 8; ++rr)
#pragma unroll
                for (int ee = 0; ee < 4; ++ee) {
                    A01[rr][ee] = pkfma(xf[rr].lo, cbf[ee].lo, A01[rr][ee]);
                    A23[rr][ee] = pkfma(xf[rr].hi, cbf[ee].hi, A23[rr][ee]);
                }
        }

        // tile epilogue: dist + running argmin (entries ascend per lane)
#pragma unroll
        for (int rr = 0; rr < 8; ++rr)
#pragma unroll
            for (int ee = 0; ee < 4; ++ee) {
                const float dot = (A01[rr][ee].x + A01[rr][ee].y) +
                                  (A23[rr][ee].x + A23[rr][ee].y);
                const float dist = fmaf(-2.f, dot, xs[rr] + cq4[ee]);
                const int e = e0 + ee;
                if (dist < bestd[rr]) {  // strict <: first occurrence
                    bestd[rr] = dist;
                    bib[rr] = e;
                }
            }
    }

    // ---- cross-lane combine over ci (disjoint entry sets; tie -> lower) ----
#pragma unroll
    for (int rr = 0; rr < 8; ++rr) {
#pragma unroll
        for (int m = 1; m <= 4; m <<= 1) {
            const float od = __shfl_xor(bestd[rr], m, 64);
            const int oi = __shfl_xor(bib[rr], m, 64);
            if (od < bestd[rr] || (od == bestd[rr] && oi < bib[rr])) {
                bestd[rr] = od;
                bib[rr] = oi;
            }
        }
    }

    // order this wave's zero-stores before its 1.0 scatter (same rows)
    asm volatile("s_waitcnt vmcnt(0)" ::: "memory");

    if (ci == 0) {
#pragma unroll
        for (int rr = 0; rr < 8; ++rr) {
            const int n = row0 + rr;
            idxf[(size_t)n * NCB + k] = (float)bib[rr];
            const f32x4* src = cbk4 + (size_t)bib[rr] * 8;
            f32x4* dst = (f32x4*)(xhat + ((size_t)n * NCB + k) * DIM);
#pragma unroll
            for (int j = 0; j < 8; ++j) dst[j] = src[j];
            onehot[((size_t)n * NCB + k) * CB + bib[rr]] = 1.0f;
        }
    }
}

extern "C" void kernel_launch(void* const* d_in, const int* in_sizes, int n_in,
                              void* d_out, int out_size, void* d_ws,
                              size_t ws_size, hipStream_t stream) {
    const float* x = (const float*)d_in[0];
    const float* cb = (const float*)d_in[1];
    const float* rb = (const float*)d_in[2];

    float* out = (float*)d_out;
    float* xhat = out;                             // N*NCB*DIM
    float* onehot = out + (size_t)NN * NCB * DIM;  // N*NCB*CB
    float* idxf = onehot + (size_t)NN * NCB * CB;  // N*NCB

    float* csqb = (float*)d_ws;     // 32 KB
    float* xsqb = csqb + NCB * CB;  // 512 KB

    const int pre_total = NCB * CB + NN * NCB;
    vq_pre<<<(pre_total + 255) / 256, 256, 0, stream>>>(cb, rb, x, csqb, xsqb);
    vq_fused<<<(NN / 512) * NCB, 512, 0, stream>>>(x, cb, csqb, xsqb, xhat,
                                                   onehot, idxf);
}

// Round 15
// 207.123 us; speedup vs baseline: 3.0002x; 3.0002x over previous
//
#include <hip/hip_runtime.h>

typedef float f32x4 __attribute__((ext_vector_type(4)));

#define NN 16384
#define NCB 8
#define DIM 32
#define CB 1024
#define RPB 256  // rows per block (one k)
#define QC 256   // codebook entries per wave (quarter)

// Kernel A: csqb[k*CB+c] = ||codebook[k,c]||^2 + rate_bias[k,c] (frozen chain)
__global__ __launch_bounds__(256) void vq_csq(const float* __restrict__ cb,
                                              const float* __restrict__ rb,
                                              float* __restrict__ out) {
    int i = blockIdx.x * 256 + threadIdx.x;
    if (i >= NCB * CB) return;
    const f32x4* c4 = (const f32x4*)(cb + (size_t)i * DIM);
    float s0 = 0.f, s1 = 0.f, s2 = 0.f, s3 = 0.f;
#pragma unroll
    for (int j = 0; j < 8; ++j) {
        f32x4 v = c4[j];
        s0 = fmaf(v.x, v.x, s0);
        s1 = fmaf(v.y, v.y, s1);
        s2 = fmaf(v.z, v.z, s2);
        s3 = fmaf(v.w, v.w, s3);
    }
    out[i] = ((s0 + s1) + (s2 + s3)) + rb[i];
}

// Fused kernel: 512 blocks (2/CU) x 512 threads (8 waves -> 4 waves/SIMD).
// Codebook entries travel the SCALAR path: the entry address is wave-uniform
// (readfirstlane'd quarter base -> provably uniform) so clang emits
// s_load_dwordx16 into SGPRs; v_fma v,v,s consumes them with ZERO per-lane
// LDS/VMEM traffic. No cb staging, no LDS in the loop: per entry = 2 scalar
// loads + 1 paced zero-store (every other entry) + 64 scalar fmaf (frozen
// d0..d3 chain, bit-identical to R2-R8) + argmin update. The only VMEM in
// each wave's FIFO is its own zero-stores, drained ONCE by the final
// __syncthreads before the 1.0 scatter. Wave (rh, q): row-half rh (lane owns
// 2 consecutive rows), entry quarter q (ascending -> strict < + ordered
// combine = exact np argmin first-occurrence).
__global__ __launch_bounds__(512, 2) void vq_fused(
    const float* __restrict__ x, const float* __restrict__ cb,
    const float* __restrict__ csqb, float* __restrict__ xhat,
    float* __restrict__ onehot, float* __restrict__ idxf) {
    __shared__ float pd[4][RPB];  // 4 KB
    __shared__ int pi[4][RPB];    // 4 KB

    const int tid = threadIdx.x;
    const int w = tid >> 6;
    const int lane = tid & 63;
    const int rh = w >> 2;                                     // row half
    const int q = __builtin_amdgcn_readfirstlane(w & 3);       // UNIFORM quarter
    const int k = blockIdx.x & (NCB - 1);
    const int n0 = (blockIdx.x >> 3) * RPB;

    const float* cbk = cb + (size_t)k * CB * DIM;
    const f32x4* cbk4 = (const f32x4*)cbk;
    const float* cqk = csqb + (size_t)k * CB;

    // ---- 2 x-rows -> registers; ||x||^2 (frozen chain) ----
    const int rbase = rh * 128 + lane * 2;
    f32x4 xr[2][8];
    float xsq[2];
#pragma unroll
    for (int j = 0; j < 2; ++j) {
        const int n = n0 + rbase + j;
        const f32x4* xp = (const f32x4*)(x + ((size_t)n * NCB + k) * DIM);
#pragma unroll
        for (int jj = 0; jj < 8; ++jj) xr[j][jj] = xp[jj];
        float q0 = 0.f, q1 = 0.f, q2 = 0.f, q3 = 0.f;
#pragma unroll
        for (int jj = 0; jj < 8; ++jj) {
            q0 = fmaf(xr[j][jj].x, xr[j][jj].x, q0);
            q1 = fmaf(xr[j][jj].y, xr[j][jj].y, q1);
            q2 = fmaf(xr[j][jj].z, xr[j][jj].z, q2);
            q3 = fmaf(xr[j][jj].w, xr[j][jj].w, q3);
        }
        xsq[j] = (q0 + q1) + (q2 + q3);
    }

    float best[2];
    int bi[2];
#pragma unroll
    for (int j = 0; j < 2; ++j) {
        best[j] = 3.4028235e38f;
        bi[j] = 0;
    }

    const int qbase = q * QC;
    const float* cbe = cbk + (size_t)qbase * DIM;  // uniform base pointer
    float cqall[4];
#pragma unroll
    for (int i = 0; i < 4; ++i) cqall[i] = cqk[qbase + i * 64 + lane];

    float4* oh4 = (float4*)onehot;
    const float4 z4 = {0.f, 0.f, 0.f, 0.f};

#pragma unroll  // g static -> cqall[g] statically indexed (stays in regs)
    for (int g = 0; g < 4; ++g) {
        const float cql = cqall[g];
#pragma unroll 2
        for (int cc = 0; cc < 64; ++cc) {
            const int e = g * 64 + cc;

            // paced zero-fill: wave owns rows [w*32,+32); 128 stores/256 iters
            if ((e & 1) == 0) {
                const int s = e >> 1;
                oh4[((size_t)(n0 + w * 32 + (s >> 2)) * NCB + k) * 256 +
                    (s & 3) * 64 + lane] = z4;
            }

            // uniform cb entry -> scalar loads (s_load_dwordx16 x2)
            const f32x4* ep = (const f32x4*)(cbe + (size_t)e * DIM);
            f32x4 A[8];
#pragma unroll
            for (int jj = 0; jj < 8; ++jj) A[jj] = ep[jj];

            const float cqv = __int_as_float(
                __builtin_amdgcn_readlane(__float_as_int(cql), cc));
            const int cg = qbase + e;

#pragma unroll
            for (int j = 0; j < 2; ++j) {
                // frozen round-2 chain order: d0..d3, jj ascending
                float d0 = 0.f, d1 = 0.f, d2 = 0.f, d3 = 0.f;
#pragma unroll
                for (int jj = 0; jj < 8; ++jj) {
                    d0 = fmaf(xr[j][jj].x, A[jj].x, d0);
                    d1 = fmaf(xr[j][jj].y, A[jj].y, d1);
                    d2 = fmaf(xr[j][jj].z, A[jj].z, d2);
                    d3 = fmaf(xr[j][jj].w, A[jj].w, d3);
                }
                const float dot = (d0 + d1) + (d2 + d3);
                const float dist = fmaf(-2.f, dot, xsq[j] + cqv);
                if (dist < best[j]) {  // strict <: first occurrence in quarter
                    best[j] = dist;
                    bi[j] = cg;
                }
            }
        }
    }

    // ---- publish per-quarter partials ----
#pragma unroll
    for (int j = 0; j < 2; ++j) {
        pd[q][rbase + j] = best[j];
        pi[q][rbase + j] = bi[j];
    }
    __syncthreads();  // partials visible + ALL zero-stores drained (vmcnt 0)

    // ---- combine quarters + scatter; threads 0..255 own block rows ----
    if (tid < RPB) {
        const int r = tid;
        float bd = pd[0][r];
        int bx = pi[0][r];
#pragma unroll
        for (int qq = 1; qq < 4; ++qq) {
            const float dq = pd[qq][r];
            const int iq = pi[qq][r];
            // ascending quarters => on tie keep lower (earlier) index
            if (dq < bd) {
                bd = dq;
                bx = iq;
            }
        }
        const int n = n0 + r;
        idxf[(size_t)n * NCB + k] = (float)bx;
        const f32x4* src = cbk4 + (size_t)bx * 8;
        f32x4* dst = (f32x4*)(xhat + ((size_t)n * NCB + k) * DIM);
#pragma unroll
        for (int jj = 0; jj < 8; ++jj) dst[jj] = src[jj];
        onehot[((size_t)n * NCB + k) * CB + bx] = 1.0f;
    }
}

extern "C" void kernel_launch(void* const* d_in, const int* in_sizes, int n_in,
                              void* d_out, int out_size, void* d_ws,
                              size_t ws_size, hipStream_t stream) {
    const float* x = (const float*)d_in[0];
    const float* cb = (const float*)d_in[1];
    const float* rb = (const float*)d_in[2];

    float* out = (float*)d_out;
    float* xhat = out;                             // N*NCB*DIM
    float* onehot = out + (size_t)NN * NCB * DIM;  // N*NCB*CB
    float* idxf = onehot + (size_t)NN * NCB * CB;  // N*NCB

    float* csqb = (float*)d_ws;  // NCB*CB floats = 32 KB

    vq_csq<<<(NCB * CB + 255) / 256, 256, 0, stream>>>(cb, rb, csqb);
    vq_fused<<<(NN / RPB) * NCB, 512, 0, stream>>>(x, cb, csqb, xhat, onehot,
                                                   idxf);
}

// Round 16
// 148.695 us; speedup vs baseline: 4.1792x; 1.3929x over previous
//
#include <hip/hip_runtime.h>

typedef float f32x4 __attribute__((ext_vector_type(4)));
typedef short bf16x8 __attribute__((ext_vector_type(8)));

#define NN 16384
#define NCB 8
#define DIM 32
#define CB 1024
#define RPB 512
#define EPP 512  // entries per pass (LDS holds 3 bf16 planes of EPP x DIM)
#define TPP 32   // 16-entry tiles per pass

// fp32 -> bf16 RTNE on the bit pattern (finite data only)
__device__ __forceinline__ unsigned short f2bf(float v) {
    const unsigned u = __float_as_uint(v);
    return (unsigned short)((u + 0x7FFFu + ((u >> 16) & 1u)) >> 16);
}
__device__ __forceinline__ float bf2f(unsigned short s) {
    return __uint_as_float(((unsigned)s) << 16);
}

// split x into 3 bf16 planes: x = h + m + l + r, |r| <= 2^-27 |x|
__device__ __forceinline__ void split3(const f32x4 a, const f32x4 b,
                                       bf16x8* H, bf16x8* M, bf16x8* L) {
    bf16x8 h, m, l;
#pragma unroll
    for (int j = 0; j < 8; ++j) {
        const float vv = (j < 4) ? a[j] : b[j - 4];
        const unsigned short hs = f2bf(vv);
        const float r1 = vv - bf2f(hs);        // exact (Sterbenz-type)
        const unsigned short ms = f2bf(r1);
        const float r2 = r1 - bf2f(ms);        // exact
        h[j] = (short)hs;
        m[j] = (short)ms;
        l[j] = (short)f2bf(r2);
    }
    *H = h;
    *M = m;
    *L = l;
}

// csqb[k*CB+c] = ||codebook[k,c]||^2 + rate_bias[k,c]  (frozen fp32 chain)
__global__ __launch_bounds__(256) void vq_csq(const float* __restrict__ cb,
                                              const float* __restrict__ rb,
                                              float* __restrict__ out) {
    int i = blockIdx.x * 256 + threadIdx.x;
    if (i >= NCB * CB) return;
    const f32x4* c4 = (const f32x4*)(cb + (size_t)i * DIM);
    float s0 = 0.f, s1 = 0.f, s2 = 0.f, s3 = 0.f;
#pragma unroll
    for (int j = 0; j < 8; ++j) {
        f32x4 v = c4[j];
        s0 = fmaf(v[0], v[0], s0);
        s1 = fmaf(v[1], v[1], s1);
        s2 = fmaf(v[2], v[2], s2);
        s3 = fmaf(v[3], v[3], s3);
    }
    out[i] = ((s0 + s1) + (s2 + s3)) + rb[i];
}

// Fused MFMA kernel: 256 blocks (1/CU) x 512 threads (8 waves).
// dist = xsq + cq - 2 x.c ; argmin only needs (cq - 2 x.c) (xsq row-const).
// x.c computed EXACTLY-ENOUGH (err ~2^-26 rel, below the ~1e-5 inter-chain
// noise that matched np's argmin in 12 prior passing rounds) via 3-way bf16
// splits and 6 MFMAs: hh + hm + mh + mm + hl + lh, fp32 accumulation.
// Wave w owns rows [w*64,+64) (4 M-tiles); per 16-entry N-tile: 3 ds_read_b128
// (B-frags, conflict-free) + 1 ds_read_b32 (cq) + 24 MFMA + epilogue.
// The loop's ONLY VMEM ops are the paced one_hot zero-stores -> nothing waits
// on them until the final per-wave vmcnt(0). 1024 entries done in 2 passes of
// 512 (LDS restage between; those barriers drain stores that must drain
// anyway). Per-lane entries ascend + strict < ; cross-lane lexicographic
// (dist, idx) reduce => exact np argmin first-occurrence.
__global__ __launch_bounds__(512, 2) void vq_fused(
    const float* __restrict__ x, const float* __restrict__ cb,
    const float* __restrict__ csqb, float* __restrict__ xhat,
    float* __restrict__ onehot, float* __restrict__ idxf) {
    __shared__ short cH[EPP * DIM];        // 32 KB
    __shared__ short cM[EPP * DIM];        // 32 KB
    __shared__ short cL[EPP * DIM];        // 32 KB
    __shared__ float sCq[CB];              // 4 KB
    __shared__ unsigned short sIdx[RPB];   // 1 KB   -> ~101 KB: 1 block/CU

    const int tid = threadIdx.x;
    const int w = tid >> 6;
    const int lane = tid & 63;
    const int l15 = lane & 15;
    const int l4 = lane >> 4;
    const int k = blockIdx.x & (NCB - 1);
    const int n0 = (blockIdx.x >> 3) * RPB;

    const float* cbk = cb + (size_t)k * CB * DIM;

    // ---- x A-fragments (4 M-tiles x 3 planes, 48 VGPRs), loaded once ----
    // A-frag layout (16x16x32): row = lane&15, k = (lane>>4)*8 + j
    bf16x8 xh[4], xm[4], xl[4];
#pragma unroll
    for (int mt = 0; mt < 4; ++mt) {
        const int row = n0 + w * 64 + mt * 16 + l15;
        const float* xp = x + ((size_t)row * NCB + k) * DIM + l4 * 8;
        split3(*(const f32x4*)xp, *(const f32x4*)(xp + 4), &xh[mt], &xm[mt],
               &xl[mt]);
    }

    // ---- stage pass-0 c planes; B-frag-pattern writes (conflict-free) ----
    // B-frag layout: col(entry) = lane&15, k = (lane>>4)*8 + j
#pragma unroll
    for (int rd = 0; rd < 4; ++rd) {
        const int eLoc = w * 64 + rd * 16 + l15;
        const float* src = cbk + (size_t)eLoc * DIM + l4 * 8;
        bf16x8 h, m, l;
        split3(*(const f32x4*)src, *(const f32x4*)(src + 4), &h, &m, &l);
        const int so = eLoc * DIM + l4 * 8;
        *(bf16x8*)&cH[so] = h;
        *(bf16x8*)&cM[so] = m;
        *(bf16x8*)&cL[so] = l;
    }
    sCq[tid] = csqb[(size_t)k * CB + tid];
    sCq[tid + 512] = csqb[(size_t)k * CB + tid + 512];
    __syncthreads();  // staged; no stores outstanding yet

    float best[4][4];
    int bidx[4][4];
#pragma unroll
    for (int mt = 0; mt < 4; ++mt)
#pragma unroll
        for (int r = 0; r < 4; ++r) {
            best[mt][r] = 3.4028235e38f;
            bidx[mt][r] = 0;
        }

    const f32x4 z4 = {0.f, 0.f, 0.f, 0.f};

    for (int p = 0; p < 2; ++p) {
        if (p) {
            __syncthreads();  // everyone done reading pass-0 planes
#pragma unroll
            for (int rd = 0; rd < 4; ++rd) {
                const int eLoc = w * 64 + rd * 16 + l15;
                const float* src =
                    cbk + (size_t)(EPP + eLoc) * DIM + l4 * 8;
                bf16x8 h, m, l;
                split3(*(const f32x4*)src, *(const f32x4*)(src + 4), &h, &m,
                       &l);
                const int so = eLoc * DIM + l4 * 8;
                *(bf16x8*)&cH[so] = h;
                *(bf16x8*)&cM[so] = m;
                *(bf16x8*)&cL[so] = l;
            }
            __syncthreads();
        }

#pragma unroll 2
        for (int tt = 0; tt < TPP; ++tt) {
            // zero-fill: one full one_hot row of this wave per tile (4 KB)
            {
                f32x4* rp = (f32x4*)onehot +
                            ((size_t)(n0 + w * 64 + p * 32 + tt) * NCB + k) *
                                256;
#pragma unroll
                for (int j = 0; j < 4; ++j) rp[j * 64 + lane] = z4;
            }

            const int so = (tt * 16 + l15) * DIM + l4 * 8;
            const bf16x8 ch = *(const bf16x8*)&cH[so];
            const bf16x8 cm = *(const bf16x8*)&cM[so];
            const bf16x8 cl = *(const bf16x8*)&cL[so];
            const float cqv = sCq[p * EPP + tt * 16 + l15];
            const int eg = p * EPP + tt * 16 + l15;

#pragma unroll
            for (int mt = 0; mt < 4; ++mt) {
                f32x4 acc = {0.f, 0.f, 0.f, 0.f};
                acc = __builtin_amdgcn_mfma_f32_16x16x32_bf16(xh[mt], ch, acc,
                                                              0, 0, 0);
                acc = __builtin_amdgcn_mfma_f32_16x16x32_bf16(xh[mt], cm, acc,
                                                              0, 0, 0);
                acc = __builtin_amdgcn_mfma_f32_16x16x32_bf16(xm[mt], ch, acc,
                                                              0, 0, 0);
                acc = __builtin_amdgcn_mfma_f32_16x16x32_bf16(xm[mt], cm, acc,
                                                              0, 0, 0);
                acc = __builtin_amdgcn_mfma_f32_16x16x32_bf16(xh[mt], cl, acc,
                                                              0, 0, 0);
                acc = __builtin_amdgcn_mfma_f32_16x16x32_bf16(xl[mt], ch, acc,
                                                              0, 0, 0);
                // C/D: col(entry)=lane&15, row=(lane>>4)*4+r  [HW-verified]
#pragma unroll
                for (int r = 0; r < 4; ++r) {
                    const float dist = fmaf(-2.f, acc[r], cqv);
                    if (dist < best[mt][r]) {  // strict <: first occurrence
                        best[mt][r] = dist;
                        bidx[mt][r] = eg;
                    }
                }
            }
        }
    }

    // ---- cross-lane reduce over the 16 entry-lanes (tie -> lower idx) ----
#pragma unroll
    for (int mt = 0; mt < 4; ++mt)
#pragma unroll
        for (int r = 0; r < 4; ++r) {
            float b = best[mt][r];
            int ix = bidx[mt][r];
#pragma unroll
            for (int mask = 1; mask <= 8; mask <<= 1) {
                const float ob = __shfl_xor(b, mask, 64);
                const int oi = __shfl_xor(ix, mask, 64);
                if (ob < b || (ob == b && oi < ix)) {
                    b = ob;
                    ix = oi;
                }
            }
            if (l15 == 0)
                sIdx[w * 64 + mt * 16 + l4 * 4 + r] = (unsigned short)ix;
        }

    // same-wave LDS handoff (lgkmcnt auto); then drain this wave's zeros
    const int bx = sIdx[w * 64 + lane];
    asm volatile("s_waitcnt vmcnt(0)" ::: "memory");

    const int n = n0 + w * 64 + lane;
    idxf[(size_t)n * NCB + k] = (float)bx;
    onehot[((size_t)n * NCB + k) * CB + bx] = 1.0f;
    const f32x4* srcv = (const f32x4*)(cbk + (size_t)bx * DIM);
    f32x4* dst = (f32x4*)(xhat + ((size_t)n * NCB + k) * DIM);
#pragma unroll
    for (int j = 0; j < 8; ++j) dst[j] = srcv[j];
}

extern "C" void kernel_launch(void* const* d_in, const int* in_sizes, int n_in,
                              void* d_out, int out_size, void* d_ws,
                              size_t ws_size, hipStream_t stream) {
    const float* x = (const float*)d_in[0];
    const float* cb = (const float*)d_in[1];
    const float* rb = (const float*)d_in[2];

    float* out = (float*)d_out;
    float* xhat = out;                             // N*NCB*DIM
    float* onehot = out + (size_t)NN * NCB * DIM;  // N*NCB*CB
    float* idxf = onehot + (size_t)NN * NCB * CB;  // N*NCB

    float* csqb = (float*)d_ws;  // 32 KB

    vq_csq<<<(NCB * CB + 255) / 256, 256, 0, stream>>>(cb, rb, csqb);
    vq_fused<<<(NN / RPB) * NCB, 512, 0, stream>>>(x, cb, csqb, xhat, onehot,
                                                   idxf);
}